// Round 5
// baseline (84.882 us; speedup 1.0000x reference)
//
#include <hip/hip_runtime.h>
#include <hip/hip_bf16.h>
#include <math.h>

#define NH 1024
#define SEQ 1024
#define BATCH 2
#define NHEAD 16
#define DHEAD 64

typedef __attribute__((ext_vector_type(8))) short short8;
typedef __attribute__((ext_vector_type(4))) float f32x4;

__device__ __forceinline__ unsigned short f2bf(float f) {
    unsigned u = __builtin_bit_cast(unsigned, f);
    unsigned r = 0x7FFFu + ((u >> 16) & 1u);
    u += r;
    return (unsigned short)(u >> 16);
}
__device__ __forceinline__ unsigned pk_bf2(float lo, float hi) {
    return (unsigned)f2bf(lo) | ((unsigned)f2bf(hi) << 16);
}
__device__ __forceinline__ unsigned cvtpk_bf16(float lo, float hi) {
    unsigned r;
    asm("v_cvt_pk_bf16_f32 %0, %1, %2" : "=v"(r) : "v"(lo), "v"(hi));
    return r;
}

typedef __attribute__((address_space(1))) const unsigned int as1_uint;
typedef __attribute__((address_space(3))) unsigned int as3_uint;
__device__ __forceinline__ void gload16(const void* g, void* l) {
    __builtin_amdgcn_global_load_lds((as1_uint*)g, (as3_uint*)l, 16, 0, 0);
}

// ---------------- Kernel 1: LayerNorm per row -> bf16 xn ----------------
__global__ __launch_bounds__(256) void k_ln(const float* __restrict__ x,
                                            const float* __restrict__ g,
                                            const float* __restrict__ b,
                                            unsigned short* __restrict__ xnb) {
    int row = blockIdx.x;
    int t = threadIdx.x;
    const float4* xr = (const float4*)(x + (size_t)row * NH);
    float4 xv = xr[t];
    float s  = xv.x + xv.y + xv.z + xv.w;
    float ss = xv.x*xv.x + xv.y*xv.y + xv.z*xv.z + xv.w*xv.w;
    for (int off = 32; off > 0; off >>= 1) {
        s  += __shfl_down(s, off);
        ss += __shfl_down(ss, off);
    }
    __shared__ float ls[4], lss[4];
    int wid = t >> 6;
    if ((t & 63) == 0) { ls[wid] = s; lss[wid] = ss; }
    __syncthreads();
    s  = ls[0] + ls[1] + ls[2] + ls[3];
    ss = lss[0] + lss[1] + lss[2] + lss[3];
    float mu  = s * (1.0f / NH);
    float var = ss * (1.0f / NH) - mu * mu;
    float rstd = rsqrtf(var + 1e-5f);
    float4 gv = ((const float4*)g)[t];
    float4 bv = ((const float4*)b)[t];
    float o0 = (xv.x - mu) * rstd * gv.x + bv.x;
    float o1 = (xv.y - mu) * rstd * gv.y + bv.y;
    float o2 = (xv.z - mu) * rstd * gv.z + bv.z;
    float o3 = (xv.w - mu) * rstd * gv.w + bv.w;
    uint2 u;
    u.x = pk_bf2(o0, o1);
    u.y = pk_bf2(o2, o3);
    *(uint2*)(xnb + (size_t)row * NH + t * 4) = u;
}

// ---------------- Kernel 1b: mask factor precompute ----------------
__global__ __launch_bounds__(256) void k_mask(const float* __restrict__ mask,
                                              float* __restrict__ maskf) {
    int i = blockIdx.x * 256 + threadIdx.x;
    // (1-m) * sqrt(2)/sqrt(1024) * ln2   (ln2 folds the log2->ln conversion)
    maskf[i] = (1.0f - mask[i]) * 0.044194173824159216f * 0.69314718055994531f;
}

// ---------------- Kernel 2: Wv transpose + bf16: WvT[n][k] ----------------
__global__ __launch_bounds__(256) void k_wvt(const float* __restrict__ Wv,
                                             unsigned short* __restrict__ WvT) {
    __shared__ float T[64][65];
    int k0 = (blockIdx.x >> 4) * 64, n0 = (blockIdx.x & 15) * 64;
    int t = threadIdx.x;
    int row = t >> 2, c4 = t & 3;
#pragma unroll
    for (int s = 0; s < 4; ++s) {
        float4 v = *(const float4*)(Wv + (size_t)(k0 + row) * NH + n0 + c4 * 16 + s * 4);
        *(float4*)&T[row][c4 * 16 + s * 4] = v;
    }
    __syncthreads();
    unsigned short tmp[16] __attribute__((aligned(16)));
#pragma unroll
    for (int s = 0; s < 16; ++s) tmp[s] = f2bf(T[c4 * 16 + s][row]);
    unsigned short* dst = WvT + (size_t)(n0 + row) * NH + k0 + c4 * 16;
    *(short8*)dst = *(const short8*)&tmp[0];
    *(short8*)(dst + 8) = *(const short8*)&tmp[8];
}

// ---------------- Kernel 3: q,k projections from bf16 xn ----------------
__global__ __launch_bounds__(256) void k_qk(const unsigned short* __restrict__ xnb,
                                            const float* __restrict__ Wq,
                                            const float* __restrict__ bq,
                                            const float* __restrict__ Wk,
                                            const float* __restrict__ bk,
                                            float* __restrict__ qT,
                                            float* __restrict__ kT) {
    int t = threadIdx.x;
    int wave = t >> 6;
    int lane = t & 63;
    int row = blockIdx.x * 4 + wave;
    int h = lane & 15;
    int g = lane >> 4;
    const unsigned* xr2 = (const unsigned*)(xnb + (size_t)row * NH + g * 256);
    float qa = 0.f, ka = 0.f;
#pragma unroll 4
    for (int d2 = 0; d2 < 128; ++d2) {
        unsigned u = xr2[d2];
        float x0 = __builtin_bit_cast(float, u << 16);
        float x1 = __builtin_bit_cast(float, u & 0xFFFF0000u);
        int gd = (g * 256 + d2 * 2) * 16 + h;
        qa = fmaf(x0, Wq[gd], qa);
        ka = fmaf(x0, Wk[gd], ka);
        qa = fmaf(x1, Wq[gd + 16], qa);
        ka = fmaf(x1, Wk[gd + 16], ka);
    }
    qa += __shfl_xor(qa, 16);
    ka += __shfl_xor(ka, 16);
    qa += __shfl_xor(qa, 32);
    ka += __shfl_xor(ka, 32);
    if (g == 0) {
        qT[h * 2048 + row] = qa + bq[h];
        kT[h * 2048 + row] = ka + bk[h];
    }
}

// ---------------- Kernel 4: MFMA GEMM v = xn @ Wv + bv -> vt[b][h][d][j] bf16 ----------------
__global__ __launch_bounds__(256) void k_vmfma(const unsigned short* __restrict__ Abf,
                                               const unsigned short* __restrict__ WvT,
                                               const float* __restrict__ bias,
                                               unsigned short* __restrict__ vt) {
    __shared__ unsigned short lds[2][8192]; // per buf: A 64x64 @0 (4096), B 64x64 @4096
    int t = threadIdx.x, w = t >> 6, lane = t & 63, g = lane >> 4, r = lane & 15;
    int mt = blockIdx.x >> 4, nt_ = blockIdx.x & 15;
    int i0 = mt * 64, n0 = nt_ * 64;

    f32x4 acc[2][2];
#pragma unroll
    for (int a = 0; a < 2; ++a)
#pragma unroll
        for (int c = 0; c < 2; ++c) acc[a][c] = (f32x4)(0.0f);

    auto stage = [&](int buf, int k0) {
#pragma unroll
        for (int i = 0; i < 2; ++i) {
            int o = i * 4096 + w * 1024 + lane * 16;
            int rr = o >> 7, cb = o & 127;
            int sc = (cb ^ ((rr & 7) << 4)) >> 1;
            gload16(Abf + (size_t)(i0 + rr) * NH + k0 + sc, &lds[buf][o >> 1]);
        }
#pragma unroll
        for (int i = 0; i < 2; ++i) {
            int o = i * 4096 + w * 1024 + lane * 16;
            int rr = o >> 7, cb = o & 127;
            int sc = (cb ^ ((rr & 7) << 4)) >> 1;
            gload16(WvT + (size_t)(n0 + rr) * NH + k0 + sc, &lds[buf][4096 + (o >> 1)]);
        }
    };

    int mbase = (w >> 1) * 32, nbase = (w & 1) * 32;
    int swz = (r & 7) << 4;

    auto compute = [&](int buf) {
        const unsigned short* As = lds[buf];
        const unsigned short* Bs = lds[buf] + 4096;
#pragma unroll
        for (int ks = 0; ks < 2; ++ks) {
            int kbyte = ks * 64 + g * 16;
            int kb = kbyte ^ swz;
            short8 af[2], bfm[2];
#pragma unroll
            for (int mf = 0; mf < 2; ++mf) {
                int row = mbase + mf * 16 + r;
                af[mf] = *(const short8*)(As + ((row * 128 + kb) >> 1));
            }
#pragma unroll
            for (int nf = 0; nf < 2; ++nf) {
                int rowB = nbase + nf * 16 + r;
                bfm[nf] = *(const short8*)(Bs + ((rowB * 128 + kb) >> 1));
            }
#pragma unroll
            for (int mf = 0; mf < 2; ++mf)
#pragma unroll
                for (int nf = 0; nf < 2; ++nf)
                    acc[mf][nf] = __builtin_amdgcn_mfma_f32_16x16x32_bf16(af[mf], bfm[nf], acc[mf][nf], 0, 0, 0);
        }
    };

    stage(0, 0);
    __syncthreads();
    int cur = 0;
#pragma unroll 1
    for (int kt = 0; kt < 15; ++kt) {
        stage(cur ^ 1, (kt + 1) * 64);
        compute(cur);
        __syncthreads();
        cur ^= 1;
    }
    compute(cur);

    unsigned short (*tsm)[72] = (unsigned short(*)[72])&lds[0][0];
#pragma unroll
    for (int nf = 0; nf < 2; ++nf) {
        float bv = bias[n0 + nbase + nf * 16 + r];
#pragma unroll
        for (int mf = 0; mf < 2; ++mf)
#pragma unroll
            for (int j = 0; j < 4; ++j)
                tsm[nbase + nf * 16 + r][mbase + mf * 16 + g * 4 + j] = f2bf(acc[mf][nf][j] + bv);
    }
    __syncthreads();
    int b = mt >> 4;
    int jc0 = (mt & 15) * 64;
    int d = t >> 2, jb = (t & 3) * 16;
    unsigned short* dst = vt + ((size_t)((b * 16 + nt_) * 64 + d)) * 1024 + jc0 + jb;
    *(short8*)dst = *(const short8*)&tsm[d][jb];
    *(short8*)(dst + 8) = *(const short8*)&tsm[d][jb + 8];
}

// ---------------- Kernel 5: fused scores + MFMA PV + GELU + residual (no LDS) ----------------
__global__ __launch_bounds__(256) void k_attn(const float* __restrict__ qT,
                                              const float* __restrict__ kT,
                                              const unsigned short* __restrict__ vt,
                                              const float* __restrict__ x,
                                              const float* __restrict__ maskf,
                                              const float* __restrict__ angle,
                                              const float* __restrict__ zfp,
                                              float* __restrict__ out) {
    int blk = blockIdx.x;
    int qt = blk & 15;
    int h = (blk >> 4) & 15;
    int b = blk >> 8;
    int t = threadIdx.x;
    int w = t >> 6, lane = t & 63, g = lane >> 4, r = lane & 15;
    int i0 = qt * 64 + w * 16;

    float ang = angle[h];
    float cs = cosf(ang), sn = sinf(ang);
    float c1 = cs - sn, nc2 = -(cs + sn);
    float zf = zfp[0];
    const float L2E = 1.4426950408889634f;

    const float* qcol = qT + h * 2048 + b * 1024;
    const float* kcol = kT + h * 2048 + b * 1024;
    const float* mrow = maskf + b * 1024;
    const unsigned short* vhead = vt + ((size_t)(b * 16 + h)) * 64 * 1024;

    float qv = qcol[i0 + r];
    float c1q = c1 * qv, snq = sn * qv;

    f32x4 acc[4];
#pragma unroll
    for (int nb = 0; nb < 4; ++nb) acc[nb] = (f32x4)(0.0f);

#pragma unroll 2
    for (int it = 0; it < 32; ++it) {
        int j = it * 32 + g * 8;
        short8 bfr[4];
#pragma unroll
        for (int nb = 0; nb < 4; ++nb)
            bfr[nb] = *(const short8*)(vhead + (size_t)(nb * 16 + r) * 1024 + j);
        float4 ka = *(const float4*)(kcol + j);
        float4 kb = *(const float4*)(kcol + j + 4);
        float4 fa = *(const float4*)(mrow + j);
        float4 fb = *(const float4*)(mrow + j + 4);
        float kk[8] = {ka.x, ka.y, ka.z, ka.w, kb.x, kb.y, kb.z, kb.w};
        float ff[8] = {fa.x, fa.y, fa.z, fa.w, fb.x, fb.y, fb.z, fb.w};

        unsigned a[4];
#pragma unroll
        for (int p = 0; p < 4; ++p) {
            float s2[2];
#pragma unroll
            for (int q2 = 0; q2 < 2; ++q2) {
                float kv = kk[p * 2 + q2];
                float dd = fmaf(nc2, kv, c1q);          // real - imag
                float im = fmaf(cs, kv, snq);           // imag
                float e  = __builtin_amdgcn_exp2f(-dd * L2E);   // exp(-d)
                float sg = __builtin_amdgcn_rcpf(1.0f + e);     // sigmoid(d)
                float comp = fmaf(dd, sg, im);
                float ee = __builtin_amdgcn_exp2f(comp * L2E);  // exp(comp)
                float lg = __builtin_amdgcn_logf(1.0f + ee);    // log2(1+exp(comp))
                s2[q2] = lg * ff[p * 2 + q2];           // * (1-m)*scale*ln2
            }
            a[p] = cvtpk_bf16(s2[0], s2[1]);
        }
        unsigned av[4] = {a[0], a[1], a[2], a[3]};
        short8 af = *(short8*)av;

#pragma unroll
        for (int nb = 0; nb < 4; ++nb)
            acc[nb] = __builtin_amdgcn_mfma_f32_16x16x32_bf16(af, bfr[nb], acc[nb], 0, 0, 0);
    }

    // epilogue straight from acc: D row = g*4+jj (q-local), col = r (d within nb block)
#pragma unroll
    for (int jj = 0; jj < 4; ++jj) {
        int q_row = i0 + g * 4 + jj;
        size_t base = ((size_t)(b * 1024 + q_row)) * 1024 + h * 64 + r;
#pragma unroll
        for (int nb = 0; nb < 4; ++nb) {
            float c = acc[nb][jj];
            float gl = 0.5f * c * (1.0f + erff(c * 0.70710678118654752f));
            out[base + nb * 16] = x[base + nb * 16] + gl * zf;
        }
    }
}

extern "C" void kernel_launch(void* const* d_in, const int* in_sizes, int n_in,
                              void* d_out, int out_size, void* d_ws, size_t ws_size,
                              hipStream_t stream) {
    const float* x      = (const float*)d_in[0];
    const float* mask   = (const float*)d_in[1];
    const float* Wq     = (const float*)d_in[2];
    const float* bq     = (const float*)d_in[3];
    const float* Wk     = (const float*)d_in[4];
    const float* bk     = (const float*)d_in[5];
    const float* Wv     = (const float*)d_in[6];
    const float* bv     = (const float*)d_in[7];
    const float* ln_g   = (const float*)d_in[8];
    const float* ln_b   = (const float*)d_in[9];
    const float* zf     = (const float*)d_in[10];
    const float* angle  = (const float*)d_in[11];
    float* out = (float*)d_out;

    unsigned short* xnb = (unsigned short*)d_ws;   // 2M bf16
    unsigned short* vt  = xnb + 2097152;           // 2M bf16
    unsigned short* WvT = vt + 2097152;            // 1M bf16
    float* qT = (float*)(WvT + 1048576);           // 32K f32
    float* kT = qT + 32768;                        // 32K f32
    float* maskf = kT + 32768;                     // 2K f32

    k_wvt<<<256, 256, 0, stream>>>(Wv, WvT);
    k_ln<<<BATCH * SEQ, 256, 0, stream>>>(x, ln_g, ln_b, xnb);
    k_mask<<<8, 256, 0, stream>>>(mask, maskf);
    k_qk<<<BATCH * SEQ / 4, 256, 0, stream>>>(xnb, Wq, bq, Wk, bk, qT, kT);
    k_vmfma<<<512, 256, 0, stream>>>(xnb, WvT, bv, vt);
    k_attn<<<BATCH * NHEAD * (SEQ / 64), 256, 0, stream>>>(qT, kT, vt, x, maskf, angle, zf, out);
}

// Round 6
// 82.495 us; speedup vs baseline: 1.0289x; 1.0289x over previous
//
#include <hip/hip_runtime.h>
#include <hip/hip_bf16.h>
#include <math.h>

#define NH 1024
#define SEQ 1024
#define BATCH 2
#define NHEAD 16
#define DHEAD 64

typedef __attribute__((ext_vector_type(8))) short short8;
typedef __attribute__((ext_vector_type(4))) float f32x4;

__device__ __forceinline__ unsigned short f2bf(float f) {
    unsigned u = __builtin_bit_cast(unsigned, f);
    unsigned r = 0x7FFFu + ((u >> 16) & 1u);
    u += r;
    return (unsigned short)(u >> 16);
}
__device__ __forceinline__ unsigned pk_bf2(float lo, float hi) {
    return (unsigned)f2bf(lo) | ((unsigned)f2bf(hi) << 16);
}
__device__ __forceinline__ unsigned cvtpk_bf16(float lo, float hi) {
    unsigned r;
    asm("v_cvt_pk_bf16_f32 %0, %1, %2" : "=v"(r) : "v"(lo), "v"(hi));
    return r;
}

typedef __attribute__((address_space(1))) const unsigned int as1_uint;
typedef __attribute__((address_space(3))) unsigned int as3_uint;
__device__ __forceinline__ void gload16(const void* g, void* l) {
    __builtin_amdgcn_global_load_lds((as1_uint*)g, (as3_uint*)l, 16, 0, 0);
}

// ---------------- Kernel 1: LayerNorm per row -> bf16 xn ----------------
__global__ __launch_bounds__(256) void k_ln(const float* __restrict__ x,
                                            const float* __restrict__ g,
                                            const float* __restrict__ b,
                                            unsigned short* __restrict__ xnb) {
    int row = blockIdx.x;
    int t = threadIdx.x;
    const float4* xr = (const float4*)(x + (size_t)row * NH);
    float4 xv = xr[t];
    float s  = xv.x + xv.y + xv.z + xv.w;
    float ss = xv.x*xv.x + xv.y*xv.y + xv.z*xv.z + xv.w*xv.w;
    for (int off = 32; off > 0; off >>= 1) {
        s  += __shfl_down(s, off);
        ss += __shfl_down(ss, off);
    }
    __shared__ float ls[4], lss[4];
    int wid = t >> 6;
    if ((t & 63) == 0) { ls[wid] = s; lss[wid] = ss; }
    __syncthreads();
    s  = ls[0] + ls[1] + ls[2] + ls[3];
    ss = lss[0] + lss[1] + lss[2] + lss[3];
    float mu  = s * (1.0f / NH);
    float var = ss * (1.0f / NH) - mu * mu;
    float rstd = rsqrtf(var + 1e-5f);
    float4 gv = ((const float4*)g)[t];
    float4 bv = ((const float4*)b)[t];
    float o0 = (xv.x - mu) * rstd * gv.x + bv.x;
    float o1 = (xv.y - mu) * rstd * gv.y + bv.y;
    float o2 = (xv.z - mu) * rstd * gv.z + bv.z;
    float o3 = (xv.w - mu) * rstd * gv.w + bv.w;
    uint2 u;
    u.x = pk_bf2(o0, o1);
    u.y = pk_bf2(o2, o3);
    *(uint2*)(xnb + (size_t)row * NH + t * 4) = u;
}

// ---------------- Kernel 1b: mask factor precompute ----------------
__global__ __launch_bounds__(256) void k_mask(const float* __restrict__ mask,
                                              float* __restrict__ maskf) {
    int i = blockIdx.x * 256 + threadIdx.x;
    maskf[i] = (1.0f - mask[i]) * 0.044194173824159216f * 0.69314718055994531f;
}

// ---------------- Kernel 2: Wv transpose + bf16: WvT[n][k] ----------------
__global__ __launch_bounds__(256) void k_wvt(const float* __restrict__ Wv,
                                             unsigned short* __restrict__ WvT) {
    __shared__ float T[64][65];
    int k0 = (blockIdx.x >> 4) * 64, n0 = (blockIdx.x & 15) * 64;
    int t = threadIdx.x;
    int row = t >> 2, c4 = t & 3;
#pragma unroll
    for (int s = 0; s < 4; ++s) {
        float4 v = *(const float4*)(Wv + (size_t)(k0 + row) * NH + n0 + c4 * 16 + s * 4);
        *(float4*)&T[row][c4 * 16 + s * 4] = v;
    }
    __syncthreads();
    unsigned short tmp[16] __attribute__((aligned(16)));
#pragma unroll
    for (int s = 0; s < 16; ++s) tmp[s] = f2bf(T[c4 * 16 + s][row]);
    unsigned short* dst = WvT + (size_t)(n0 + row) * NH + k0 + c4 * 16;
    *(short8*)dst = *(const short8*)&tmp[0];
    *(short8*)(dst + 8) = *(const short8*)&tmp[8];
}

// ---------------- Kernel 3: q,k projections from bf16 xn ----------------
__global__ __launch_bounds__(256) void k_qk(const unsigned short* __restrict__ xnb,
                                            const float* __restrict__ Wq,
                                            const float* __restrict__ bq,
                                            const float* __restrict__ Wk,
                                            const float* __restrict__ bk,
                                            float* __restrict__ qT,
                                            float* __restrict__ kT) {
    int t = threadIdx.x;
    int wave = t >> 6;
    int lane = t & 63;
    int row = blockIdx.x * 4 + wave;
    int h = lane & 15;
    int g = lane >> 4;
    const unsigned* xr2 = (const unsigned*)(xnb + (size_t)row * NH + g * 256);
    float qa = 0.f, ka = 0.f;
#pragma unroll 4
    for (int d2 = 0; d2 < 128; ++d2) {
        unsigned u = xr2[d2];
        float x0 = __builtin_bit_cast(float, u << 16);
        float x1 = __builtin_bit_cast(float, u & 0xFFFF0000u);
        int gd = (g * 256 + d2 * 2) * 16 + h;
        qa = fmaf(x0, Wq[gd], qa);
        ka = fmaf(x0, Wk[gd], ka);
        qa = fmaf(x1, Wq[gd + 16], qa);
        ka = fmaf(x1, Wk[gd + 16], ka);
    }
    qa += __shfl_xor(qa, 16);
    ka += __shfl_xor(ka, 16);
    qa += __shfl_xor(qa, 32);
    ka += __shfl_xor(ka, 32);
    if (g == 0) {
        qT[h * 2048 + row] = qa + bq[h];
        kT[h * 2048 + row] = ka + bk[h];
    }
}

// ---------------- Kernel 4: MFMA GEMM v = xn @ Wv + bv -> vt[b][h][d][j] bf16 ----------------
__global__ __launch_bounds__(256) void k_vmfma(const unsigned short* __restrict__ Abf,
                                               const unsigned short* __restrict__ WvT,
                                               const float* __restrict__ bias,
                                               unsigned short* __restrict__ vt) {
    __shared__ unsigned short lds[2][8192];
    int t = threadIdx.x, w = t >> 6, lane = t & 63, g = lane >> 4, r = lane & 15;
    int mt = blockIdx.x >> 4, nt_ = blockIdx.x & 15;
    int i0 = mt * 64, n0 = nt_ * 64;

    f32x4 acc[2][2];
#pragma unroll
    for (int a = 0; a < 2; ++a)
#pragma unroll
        for (int c = 0; c < 2; ++c) acc[a][c] = (f32x4)(0.0f);

    auto stage = [&](int buf, int k0) {
#pragma unroll
        for (int i = 0; i < 2; ++i) {
            int o = i * 4096 + w * 1024 + lane * 16;
            int rr = o >> 7, cb = o & 127;
            int sc = (cb ^ ((rr & 7) << 4)) >> 1;
            gload16(Abf + (size_t)(i0 + rr) * NH + k0 + sc, &lds[buf][o >> 1]);
        }
#pragma unroll
        for (int i = 0; i < 2; ++i) {
            int o = i * 4096 + w * 1024 + lane * 16;
            int rr = o >> 7, cb = o & 127;
            int sc = (cb ^ ((rr & 7) << 4)) >> 1;
            gload16(WvT + (size_t)(n0 + rr) * NH + k0 + sc, &lds[buf][4096 + (o >> 1)]);
        }
    };

    int mbase = (w >> 1) * 32, nbase = (w & 1) * 32;
    int swz = (r & 7) << 4;

    auto compute = [&](int buf) {
        const unsigned short* As = lds[buf];
        const unsigned short* Bs = lds[buf] + 4096;
#pragma unroll
        for (int ks = 0; ks < 2; ++ks) {
            int kbyte = ks * 64 + g * 16;
            int kb = kbyte ^ swz;
            short8 af[2], bfm[2];
#pragma unroll
            for (int mf = 0; mf < 2; ++mf) {
                int row = mbase + mf * 16 + r;
                af[mf] = *(const short8*)(As + ((row * 128 + kb) >> 1));
            }
#pragma unroll
            for (int nf = 0; nf < 2; ++nf) {
                int rowB = nbase + nf * 16 + r;
                bfm[nf] = *(const short8*)(Bs + ((rowB * 128 + kb) >> 1));
            }
#pragma unroll
            for (int mf = 0; mf < 2; ++mf)
#pragma unroll
                for (int nf = 0; nf < 2; ++nf)
                    acc[mf][nf] = __builtin_amdgcn_mfma_f32_16x16x32_bf16(af[mf], bfm[nf], acc[mf][nf], 0, 0, 0);
        }
    };

    stage(0, 0);
    __syncthreads();
    int cur = 0;
#pragma unroll 1
    for (int kt = 0; kt < 15; ++kt) {
        stage(cur ^ 1, (kt + 1) * 64);
        compute(cur);
        __syncthreads();
        cur ^= 1;
    }
    compute(cur);

    unsigned short (*tsm)[72] = (unsigned short(*)[72])&lds[0][0];
#pragma unroll
    for (int nf = 0; nf < 2; ++nf) {
        float bv = bias[n0 + nbase + nf * 16 + r];
#pragma unroll
        for (int mf = 0; mf < 2; ++mf)
#pragma unroll
            for (int j = 0; j < 4; ++j)
                tsm[nbase + nf * 16 + r][mbase + mf * 16 + g * 4 + j] = f2bf(acc[mf][nf][j] + bv);
    }
    __syncthreads();
    int b = mt >> 4;
    int jc0 = (mt & 15) * 64;
    int d = t >> 2, jb = (t & 3) * 16;
    unsigned short* dst = vt + ((size_t)((b * 16 + nt_) * 64 + d)) * 1024 + jc0 + jb;
    *(short8*)dst = *(const short8*)&tsm[d][jb];
    *(short8*)(dst + 8) = *(const short8*)&tsm[d][jb + 8];
}

// ---------------- Kernel 5: fused scores + MFMA PV, 4-way j-split + prefetch ----------------
__global__ __launch_bounds__(256) void k_attn(const float* __restrict__ qT,
                                              const float* __restrict__ kT,
                                              const unsigned short* __restrict__ vt,
                                              const float* __restrict__ x,
                                              const float* __restrict__ maskf,
                                              const float* __restrict__ angle,
                                              const float* __restrict__ zfp,
                                              float* __restrict__ out) {
    // XCD-aware swizzle: blocks sharing one head's V panel cluster per XCD (2048 = 8*256)
    int bid = blockIdx.x;
    int lb = (bid & 7) * 256 + (bid >> 3);
    int qt = lb & 63;          // 64 q-tiles of 16 rows
    int h = (lb >> 6) & 15;
    int b = lb >> 10;
    int t = threadIdx.x;
    int w = t >> 6, lane = t & 63, g = lane >> 4, r = lane & 15;
    int i0 = qt * 16;

    __shared__ float red[4][3][16][20];

    float ang = angle[h];
    float cs = cosf(ang), sn = sinf(ang);
    float c1 = cs - sn, nc2 = -(cs + sn);
    float zf = zfp[0];
    const float L2E = 1.4426950408889634f;

    const float* qcol = qT + h * 2048 + b * 1024;
    const float* kcol = kT + h * 2048 + b * 1024;
    const float* mrow = maskf + b * 1024;
    const unsigned short* vhead = vt + ((size_t)(b * 16 + h)) * 64 * 1024;

    float qv = qcol[i0 + r];
    float c1q = c1 * qv, snq = sn * qv;

    f32x4 acc[4];
#pragma unroll
    for (int nb = 0; nb < 4; ++nb) acc[nb] = (f32x4)(0.0f);

    int jbase = w * 256 + g * 8;

    // prefetch buffers (double)
    short8 bfr[2][4];
    float4 kv4[2][2], ff4[2][2];
    {
        int j = jbase;
#pragma unroll
        for (int nb = 0; nb < 4; ++nb)
            bfr[0][nb] = *(const short8*)(vhead + (size_t)(nb * 16 + r) * 1024 + j);
        kv4[0][0] = *(const float4*)(kcol + j);
        kv4[0][1] = *(const float4*)(kcol + j + 4);
        ff4[0][0] = *(const float4*)(mrow + j);
        ff4[0][1] = *(const float4*)(mrow + j + 4);
    }

#pragma unroll 2
    for (int it = 0; it < 8; ++it) {
        int cur = it & 1, nxt = cur ^ 1;
        if (it < 7) {
            int jn = jbase + (it + 1) * 32;
#pragma unroll
            for (int nb = 0; nb < 4; ++nb)
                bfr[nxt][nb] = *(const short8*)(vhead + (size_t)(nb * 16 + r) * 1024 + jn);
            kv4[nxt][0] = *(const float4*)(kcol + jn);
            kv4[nxt][1] = *(const float4*)(kcol + jn + 4);
            ff4[nxt][0] = *(const float4*)(mrow + jn);
            ff4[nxt][1] = *(const float4*)(mrow + jn + 4);
        }
        float kk[8] = {kv4[cur][0].x, kv4[cur][0].y, kv4[cur][0].z, kv4[cur][0].w,
                       kv4[cur][1].x, kv4[cur][1].y, kv4[cur][1].z, kv4[cur][1].w};
        float ff[8] = {ff4[cur][0].x, ff4[cur][0].y, ff4[cur][0].z, ff4[cur][0].w,
                       ff4[cur][1].x, ff4[cur][1].y, ff4[cur][1].z, ff4[cur][1].w};

        unsigned a[4];
#pragma unroll
        for (int p = 0; p < 4; ++p) {
            float s2[2];
#pragma unroll
            for (int q2 = 0; q2 < 2; ++q2) {
                float kv = kk[p * 2 + q2];
                float dd = fmaf(nc2, kv, c1q);
                float im = fmaf(cs, kv, snq);
                float e  = __builtin_amdgcn_exp2f(-dd * L2E);
                float sg = __builtin_amdgcn_rcpf(1.0f + e);
                float comp = fmaf(dd, sg, im);
                float ee = __builtin_amdgcn_exp2f(comp * L2E);
                float lg = __builtin_amdgcn_logf(1.0f + ee);
                s2[q2] = lg * ff[p * 2 + q2];
            }
            a[p] = cvtpk_bf16(s2[0], s2[1]);
        }
        unsigned av[4] = {a[0], a[1], a[2], a[3]};
        short8 af = *(short8*)av;

#pragma unroll
        for (int nb = 0; nb < 4; ++nb)
            acc[nb] = __builtin_amdgcn_mfma_f32_16x16x32_bf16(af, bfr[cur][nb], acc[nb], 0, 0, 0);
    }

    // cross-wave reduce: wave w finalizes nb==w, ships other partials via LDS
#pragma unroll
    for (int nb = 0; nb < 4; ++nb) {
        if (nb != w) {
            int idx = w - (w > nb ? 1 : 0);
#pragma unroll
            for (int jj = 0; jj < 4; ++jj)
                red[nb][idx][g * 4 + jj][r] = acc[nb][jj];
        }
    }
    __syncthreads();

#pragma unroll
    for (int jj = 0; jj < 4; ++jj) {
        int q_row = i0 + g * 4 + jj;
        float c = acc[w][jj] + red[w][0][g * 4 + jj][r]
                             + red[w][1][g * 4 + jj][r]
                             + red[w][2][g * 4 + jj][r];
        float gl = 0.5f * c * (1.0f + erff(c * 0.70710678118654752f));
        size_t base = ((size_t)(b * 1024 + q_row)) * 1024 + h * 64 + w * 16 + r;
        out[base] = x[base] + gl * zf;
    }
}

extern "C" void kernel_launch(void* const* d_in, const int* in_sizes, int n_in,
                              void* d_out, int out_size, void* d_ws, size_t ws_size,
                              hipStream_t stream) {
    const float* x      = (const float*)d_in[0];
    const float* mask   = (const float*)d_in[1];
    const float* Wq     = (const float*)d_in[2];
    const float* bq     = (const float*)d_in[3];
    const float* Wk     = (const float*)d_in[4];
    const float* bk     = (const float*)d_in[5];
    const float* Wv     = (const float*)d_in[6];
    const float* bv     = (const float*)d_in[7];
    const float* ln_g   = (const float*)d_in[8];
    const float* ln_b   = (const float*)d_in[9];
    const float* zf     = (const float*)d_in[10];
    const float* angle  = (const float*)d_in[11];
    float* out = (float*)d_out;

    unsigned short* xnb = (unsigned short*)d_ws;   // 2M bf16
    unsigned short* vt  = xnb + 2097152;           // 2M bf16
    unsigned short* WvT = vt + 2097152;            // 1M bf16
    float* qT = (float*)(WvT + 1048576);           // 32K f32
    float* kT = qT + 32768;                        // 32K f32
    float* maskf = kT + 32768;                     // 2K f32

    k_wvt<<<256, 256, 0, stream>>>(Wv, WvT);
    k_ln<<<BATCH * SEQ, 256, 0, stream>>>(x, ln_g, ln_b, xnb);
    k_mask<<<8, 256, 0, stream>>>(mask, maskf);
    k_qk<<<BATCH * SEQ / 4, 256, 0, stream>>>(xnb, Wq, bq, Wk, bk, qT, kT);
    k_vmfma<<<512, 256, 0, stream>>>(xnb, WvT, bv, vt);
    k_attn<<<BATCH * NHEAD * (SEQ / 16), 256, 0, stream>>>(qT, kT, vt, x, maskf, angle, zf, out);
}

// Round 7
// 73.051 us; speedup vs baseline: 1.1620x; 1.1293x over previous
//
#include <hip/hip_runtime.h>
#include <hip/hip_bf16.h>
#include <math.h>

#define NH 1024
#define SEQ 1024
#define BATCH 2
#define NHEAD 16
#define DHEAD 64

typedef __attribute__((ext_vector_type(8))) short short8;
typedef __attribute__((ext_vector_type(4))) float f32x4;

__device__ __forceinline__ unsigned short f2bf(float f) {
    unsigned u = __builtin_bit_cast(unsigned, f);
    unsigned r = 0x7FFFu + ((u >> 16) & 1u);
    u += r;
    return (unsigned short)(u >> 16);
}
__device__ __forceinline__ unsigned pk_bf2(float lo, float hi) {
    return (unsigned)f2bf(lo) | ((unsigned)f2bf(hi) << 16);
}
__device__ __forceinline__ unsigned cvtpk_bf16(float lo, float hi) {
    unsigned r;
    asm("v_cvt_pk_bf16_f32 %0, %1, %2" : "=v"(r) : "v"(lo), "v"(hi));
    return r;
}

typedef __attribute__((address_space(1))) const unsigned int as1_uint;
typedef __attribute__((address_space(3))) unsigned int as3_uint;
__device__ __forceinline__ void gload16(const void* g, void* l) {
    __builtin_amdgcn_global_load_lds((as1_uint*)g, (as3_uint*)l, 16, 0, 0);
}

// ---------------- Kernel 1: LayerNorm per row -> bf16 xn ----------------
__global__ __launch_bounds__(256) void k_ln(const float* __restrict__ x,
                                            const float* __restrict__ g,
                                            const float* __restrict__ b,
                                            unsigned short* __restrict__ xnb) {
    int row = blockIdx.x;
    int t = threadIdx.x;
    const float4* xr = (const float4*)(x + (size_t)row * NH);
    float4 xv = xr[t];
    float s  = xv.x + xv.y + xv.z + xv.w;
    float ss = xv.x*xv.x + xv.y*xv.y + xv.z*xv.z + xv.w*xv.w;
    for (int off = 32; off > 0; off >>= 1) {
        s  += __shfl_down(s, off);
        ss += __shfl_down(ss, off);
    }
    __shared__ float ls[4], lss[4];
    int wid = t >> 6;
    if ((t & 63) == 0) { ls[wid] = s; lss[wid] = ss; }
    __syncthreads();
    s  = ls[0] + ls[1] + ls[2] + ls[3];
    ss = lss[0] + lss[1] + lss[2] + lss[3];
    float mu  = s * (1.0f / NH);
    float var = ss * (1.0f / NH) - mu * mu;
    float rstd = rsqrtf(var + 1e-5f);
    float4 gv = ((const float4*)g)[t];
    float4 bv = ((const float4*)b)[t];
    float o0 = (xv.x - mu) * rstd * gv.x + bv.x;
    float o1 = (xv.y - mu) * rstd * gv.y + bv.y;
    float o2 = (xv.z - mu) * rstd * gv.z + bv.z;
    float o3 = (xv.w - mu) * rstd * gv.w + bv.w;
    uint2 u;
    u.x = pk_bf2(o0, o1);
    u.y = pk_bf2(o2, o3);
    *(uint2*)(xnb + (size_t)row * NH + t * 4) = u;
}

// ---------------- Kernel 1b: mask factor precompute ----------------
__global__ __launch_bounds__(256) void k_mask(const float* __restrict__ mask,
                                              float* __restrict__ maskf) {
    int i = blockIdx.x * 256 + threadIdx.x;
    maskf[i] = (1.0f - mask[i]) * 0.044194173824159216f * 0.69314718055994531f;
}

// ---------------- Kernel 2: Wv transpose + bf16: WvT[n][k] ----------------
__global__ __launch_bounds__(256) void k_wvt(const float* __restrict__ Wv,
                                             unsigned short* __restrict__ WvT) {
    __shared__ float T[64][65];
    int k0 = (blockIdx.x >> 4) * 64, n0 = (blockIdx.x & 15) * 64;
    int t = threadIdx.x;
    int row = t >> 2, c4 = t & 3;
#pragma unroll
    for (int s = 0; s < 4; ++s) {
        float4 v = *(const float4*)(Wv + (size_t)(k0 + row) * NH + n0 + c4 * 16 + s * 4);
        *(float4*)&T[row][c4 * 16 + s * 4] = v;
    }
    __syncthreads();
    unsigned short tmp[16] __attribute__((aligned(16)));
#pragma unroll
    for (int s = 0; s < 16; ++s) tmp[s] = f2bf(T[c4 * 16 + s][row]);
    unsigned short* dst = WvT + (size_t)(n0 + row) * NH + k0 + c4 * 16;
    *(short8*)dst = *(const short8*)&tmp[0];
    *(short8*)(dst + 8) = *(const short8*)&tmp[8];
}

// ---------------- Kernel 3: q,k projections from bf16 xn ----------------
__global__ __launch_bounds__(256) void k_qk(const unsigned short* __restrict__ xnb,
                                            const float* __restrict__ Wq,
                                            const float* __restrict__ bq,
                                            const float* __restrict__ Wk,
                                            const float* __restrict__ bk,
                                            float* __restrict__ qT,
                                            float* __restrict__ kT) {
    int t = threadIdx.x;
    int wave = t >> 6;
    int lane = t & 63;
    int row = blockIdx.x * 4 + wave;
    int h = lane & 15;
    int g = lane >> 4;
    const unsigned* xr2 = (const unsigned*)(xnb + (size_t)row * NH + g * 256);
    float qa = 0.f, ka = 0.f;
#pragma unroll 4
    for (int d2 = 0; d2 < 128; ++d2) {
        unsigned u = xr2[d2];
        float x0 = __builtin_bit_cast(float, u << 16);
        float x1 = __builtin_bit_cast(float, u & 0xFFFF0000u);
        int gd = (g * 256 + d2 * 2) * 16 + h;
        qa = fmaf(x0, Wq[gd], qa);
        ka = fmaf(x0, Wk[gd], ka);
        qa = fmaf(x1, Wq[gd + 16], qa);
        ka = fmaf(x1, Wk[gd + 16], ka);
    }
    qa += __shfl_xor(qa, 16);
    ka += __shfl_xor(ka, 16);
    qa += __shfl_xor(qa, 32);
    ka += __shfl_xor(ka, 32);
    if (g == 0) {
        qT[h * 2048 + row] = qa + bq[h];
        kT[h * 2048 + row] = ka + bk[h];
    }
}

// ---------------- Kernel 4: MFMA GEMM v = xn @ Wv + bv -> vt[b][h][d][j] bf16 ----------------
__global__ __launch_bounds__(256) void k_vmfma(const unsigned short* __restrict__ Abf,
                                               const unsigned short* __restrict__ WvT,
                                               const float* __restrict__ bias,
                                               unsigned short* __restrict__ vt) {
    __shared__ unsigned short lds[2][8192];
    int t = threadIdx.x, w = t >> 6, lane = t & 63, g = lane >> 4, r = lane & 15;
    int mt = blockIdx.x >> 4, nt_ = blockIdx.x & 15;
    int i0 = mt * 64, n0 = nt_ * 64;

    f32x4 acc[2][2];
#pragma unroll
    for (int a = 0; a < 2; ++a)
#pragma unroll
        for (int c = 0; c < 2; ++c) acc[a][c] = (f32x4)(0.0f);

    auto stage = [&](int buf, int k0) {
#pragma unroll
        for (int i = 0; i < 2; ++i) {
            int o = i * 4096 + w * 1024 + lane * 16;
            int rr = o >> 7, cb = o & 127;
            int sc = (cb ^ ((rr & 7) << 4)) >> 1;
            gload16(Abf + (size_t)(i0 + rr) * NH + k0 + sc, &lds[buf][o >> 1]);
        }
#pragma unroll
        for (int i = 0; i < 2; ++i) {
            int o = i * 4096 + w * 1024 + lane * 16;
            int rr = o >> 7, cb = o & 127;
            int sc = (cb ^ ((rr & 7) << 4)) >> 1;
            gload16(WvT + (size_t)(n0 + rr) * NH + k0 + sc, &lds[buf][4096 + (o >> 1)]);
        }
    };

    int mbase = (w >> 1) * 32, nbase = (w & 1) * 32;
    int swz = (r & 7) << 4;

    auto compute = [&](int buf) {
        const unsigned short* As = lds[buf];
        const unsigned short* Bs = lds[buf] + 4096;
#pragma unroll
        for (int ks = 0; ks < 2; ++ks) {
            int kbyte = ks * 64 + g * 16;
            int kb = kbyte ^ swz;
            short8 af[2], bfm[2];
#pragma unroll
            for (int mf = 0; mf < 2; ++mf) {
                int row = mbase + mf * 16 + r;
                af[mf] = *(const short8*)(As + ((row * 128 + kb) >> 1));
            }
#pragma unroll
            for (int nf = 0; nf < 2; ++nf) {
                int rowB = nbase + nf * 16 + r;
                bfm[nf] = *(const short8*)(Bs + ((rowB * 128 + kb) >> 1));
            }
#pragma unroll
            for (int mf = 0; mf < 2; ++mf)
#pragma unroll
                for (int nf = 0; nf < 2; ++nf)
                    acc[mf][nf] = __builtin_amdgcn_mfma_f32_16x16x32_bf16(af[mf], bfm[nf], acc[mf][nf], 0, 0, 0);
        }
    };

    stage(0, 0);
    __syncthreads();
    int cur = 0;
#pragma unroll 1
    for (int kt = 0; kt < 15; ++kt) {
        stage(cur ^ 1, (kt + 1) * 64);
        compute(cur);
        __syncthreads();
        cur ^= 1;
    }
    compute(cur);

    unsigned short (*tsm)[72] = (unsigned short(*)[72])&lds[0][0];
#pragma unroll
    for (int nf = 0; nf < 2; ++nf) {
        float bv = bias[n0 + nbase + nf * 16 + r];
#pragma unroll
        for (int mf = 0; mf < 2; ++mf)
#pragma unroll
            for (int j = 0; j < 4; ++j)
                tsm[nbase + nf * 16 + r][mbase + mf * 16 + g * 4 + j] = f2bf(acc[mf][nf][j] + bv);
    }
    __syncthreads();
    int b = mt >> 4;
    int jc0 = (mt & 15) * 64;
    int d = t >> 2, jb = (t & 3) * 16;
    unsigned short* dst = vt + ((size_t)((b * 16 + nt_) * 64 + d)) * 1024 + jc0 + jb;
    *(short8*)dst = *(const short8*)&tsm[d][jb];
    *(short8*)(dst + 8) = *(const short8*)&tsm[d][jb + 8];
}

// ---------------- Kernel 5: fused scores + MFMA PV, 32q/block, 4-way j-split ----------------
__global__ __launch_bounds__(256, 4) void k_attn(const float* __restrict__ qT,
                                                 const float* __restrict__ kT,
                                                 const unsigned short* __restrict__ vt,
                                                 const float* __restrict__ x,
                                                 const float* __restrict__ maskf,
                                                 const float* __restrict__ angle,
                                                 const float* __restrict__ zfp,
                                                 float* __restrict__ out) {
    // XCD-aware swizzle: 1024 = 8 * 128
    int bid = blockIdx.x;
    int lb = (bid & 7) * 128 + (bid >> 3);
    int qt = lb & 31;          // 32 q-tiles of 32 rows
    int h = (lb >> 5) & 15;
    int b = lb >> 9;
    int t = threadIdx.x;
    int w = t >> 6, lane = t & 63, g = lane >> 4, r = lane & 15;
    int i0 = qt * 32;

    __shared__ float red[4][3][32][20];

    float ang = angle[h];
    float cs = cosf(ang), sn = sinf(ang);
    float c1 = cs - sn, nc2 = -(cs + sn);
    float zf = zfp[0];
    const float L2E = 1.4426950408889634f;

    const float* qcol = qT + h * 2048 + b * 1024;
    const float* kcol = kT + h * 2048 + b * 1024;
    const float* mrow = maskf + b * 1024;
    const unsigned short* vhead = vt + ((size_t)(b * 16 + h)) * 64 * 1024;

    float qv0 = qcol[i0 + r];
    float qv1 = qcol[i0 + 16 + r];
    float c1q0 = c1 * qv0, snq0 = sn * qv0;
    float c1q1 = c1 * qv1, snq1 = sn * qv1;

    f32x4 acc[2][4];
#pragma unroll
    for (int m = 0; m < 2; ++m)
#pragma unroll
        for (int nb = 0; nb < 4; ++nb) acc[m][nb] = (f32x4)(0.0f);

    int jbase = w * 256 + g * 8;

    short8 bfr[2][4];
#pragma unroll
    for (int nb = 0; nb < 4; ++nb)
        bfr[0][nb] = *(const short8*)(vhead + (size_t)(nb * 16 + r) * 1024 + jbase);

#pragma unroll 2
    for (int it = 0; it < 8; ++it) {
        int cur = it & 1, nxt = cur ^ 1;
        int j = jbase + it * 32;
        if (it < 7) {
            int jn = j + 32;
#pragma unroll
            for (int nb = 0; nb < 4; ++nb)
                bfr[nxt][nb] = *(const short8*)(vhead + (size_t)(nb * 16 + r) * 1024 + jn);
        }
        float4 ka = *(const float4*)(kcol + j);
        float4 kb = *(const float4*)(kcol + j + 4);
        float4 fa = *(const float4*)(mrow + j);
        float4 fb = *(const float4*)(mrow + j + 4);
        float kk[8] = {ka.x, ka.y, ka.z, ka.w, kb.x, kb.y, kb.z, kb.w};
        float ff[8] = {fa.x, fa.y, fa.z, fa.w, fb.x, fb.y, fb.z, fb.w};

        unsigned a0[4], a1[4];
#pragma unroll
        for (int p = 0; p < 4; ++p) {
            float s0[2], s1[2];
#pragma unroll
            for (int q2 = 0; q2 < 2; ++q2) {
                float kv = kk[p * 2 + q2];
                float f  = ff[p * 2 + q2];
                float ck = nc2 * kv;
                float ik = cs * kv;
                // q-frag 0
                float dd = c1q0 + ck;
                float im = snq0 + ik;
                float e  = __builtin_amdgcn_exp2f(-dd * L2E);
                float sg = __builtin_amdgcn_rcpf(1.0f + e);
                float comp = fmaf(dd, sg, im);
                float ee = __builtin_amdgcn_exp2f(comp * L2E);
                s0[q2] = __builtin_amdgcn_logf(1.0f + ee) * f;
                // q-frag 1
                float dd1 = c1q1 + ck;
                float im1 = snq1 + ik;
                float e1  = __builtin_amdgcn_exp2f(-dd1 * L2E);
                float sg1 = __builtin_amdgcn_rcpf(1.0f + e1);
                float comp1 = fmaf(dd1, sg1, im1);
                float ee1 = __builtin_amdgcn_exp2f(comp1 * L2E);
                s1[q2] = __builtin_amdgcn_logf(1.0f + ee1) * f;
            }
            a0[p] = cvtpk_bf16(s0[0], s0[1]);
            a1[p] = cvtpk_bf16(s1[0], s1[1]);
        }
        unsigned av0[4] = {a0[0], a0[1], a0[2], a0[3]};
        unsigned av1[4] = {a1[0], a1[1], a1[2], a1[3]};
        short8 af0 = *(short8*)av0;
        short8 af1 = *(short8*)av1;

#pragma unroll
        for (int nb = 0; nb < 4; ++nb) {
            acc[0][nb] = __builtin_amdgcn_mfma_f32_16x16x32_bf16(af0, bfr[cur][nb], acc[0][nb], 0, 0, 0);
            acc[1][nb] = __builtin_amdgcn_mfma_f32_16x16x32_bf16(af1, bfr[cur][nb], acc[1][nb], 0, 0, 0);
        }
    }

    // cross-wave reduce: wave w owns nb==w
#pragma unroll
    for (int nb = 0; nb < 4; ++nb) {
        if (nb != w) {
            int idx = w - (w > nb ? 1 : 0);
#pragma unroll
            for (int m = 0; m < 2; ++m)
#pragma unroll
                for (int jj = 0; jj < 4; ++jj)
                    red[nb][idx][m * 16 + g * 4 + jj][r] = acc[m][nb][jj];
        }
    }
    __syncthreads();

#pragma unroll
    for (int m = 0; m < 2; ++m)
#pragma unroll
        for (int jj = 0; jj < 4; ++jj) {
            int lrow = m * 16 + g * 4 + jj;
            float c = acc[m][w][jj] + red[w][0][lrow][r]
                                    + red[w][1][lrow][r]
                                    + red[w][2][lrow][r];
            float gl = 0.5f * c * (1.0f + erff(c * 0.70710678118654752f));
            size_t base = ((size_t)(b * 1024 + i0 + lrow)) * 1024 + h * 64 + w * 16 + r;
            out[base] = x[base] + gl * zf;
        }
}

extern "C" void kernel_launch(void* const* d_in, const int* in_sizes, int n_in,
                              void* d_out, int out_size, void* d_ws, size_t ws_size,
                              hipStream_t stream) {
    const float* x      = (const float*)d_in[0];
    const float* mask   = (const float*)d_in[1];
    const float* Wq     = (const float*)d_in[2];
    const float* bq     = (const float*)d_in[3];
    const float* Wk     = (const float*)d_in[4];
    const float* bk     = (const float*)d_in[5];
    const float* Wv     = (const float*)d_in[6];
    const float* bv     = (const float*)d_in[7];
    const float* ln_g   = (const float*)d_in[8];
    const float* ln_b   = (const float*)d_in[9];
    const float* zf     = (const float*)d_in[10];
    const float* angle  = (const float*)d_in[11];
    float* out = (float*)d_out;

    unsigned short* xnb = (unsigned short*)d_ws;   // 2M bf16
    unsigned short* vt  = xnb + 2097152;           // 2M bf16
    unsigned short* WvT = vt + 2097152;            // 1M bf16
    float* qT = (float*)(WvT + 1048576);           // 32K f32
    float* kT = qT + 32768;                        // 32K f32
    float* maskf = kT + 32768;                     // 2K f32

    k_wvt<<<256, 256, 0, stream>>>(Wv, WvT);
    k_ln<<<BATCH * SEQ, 256, 0, stream>>>(x, ln_g, ln_b, xnb);
    k_mask<<<8, 256, 0, stream>>>(mask, maskf);
    k_qk<<<BATCH * SEQ / 4, 256, 0, stream>>>(xnb, Wq, bq, Wk, bk, qT, kT);
    k_vmfma<<<512, 256, 0, stream>>>(xnb, WvT, bv, vt);
    k_attn<<<BATCH * NHEAD * (SEQ / 32), 256, 0, stream>>>(qT, kT, vt, x, maskf, angle, zf, out);
}

// Round 8
// 61.653 us; speedup vs baseline: 1.3768x; 1.1849x over previous
//
#include <hip/hip_runtime.h>
#include <hip/hip_bf16.h>
#include <math.h>

#define NH 1024
#define SEQ 1024
#define BATCH 2
#define NHEAD 16
#define DHEAD 64

typedef __attribute__((ext_vector_type(8))) short short8;
typedef __attribute__((ext_vector_type(4))) float f32x4;

__device__ __forceinline__ unsigned short f2bf(float f) {
    unsigned u = __builtin_bit_cast(unsigned, f);
    unsigned r = 0x7FFFu + ((u >> 16) & 1u);
    u += r;
    return (unsigned short)(u >> 16);
}
__device__ __forceinline__ unsigned pk_bf2(float lo, float hi) {
    return (unsigned)f2bf(lo) | ((unsigned)f2bf(hi) << 16);
}
__device__ __forceinline__ unsigned cvtpk_bf16(float lo, float hi) {
    unsigned r;
    asm("v_cvt_pk_bf16_f32 %0, %1, %2" : "=v"(r) : "v"(lo), "v"(hi));
    return r;
}

typedef __attribute__((address_space(1))) const unsigned int as1_uint;
typedef __attribute__((address_space(3))) unsigned int as3_uint;
__device__ __forceinline__ void gload16(const void* g, void* l) {
    __builtin_amdgcn_global_load_lds((as1_uint*)g, (as3_uint*)l, 16, 0, 0);
}

// ---------------- Kernel 1: LayerNorm per row -> bf16 xn ----------------
__global__ __launch_bounds__(256) void k_ln(const float* __restrict__ x,
                                            const float* __restrict__ g,
                                            const float* __restrict__ b,
                                            unsigned short* __restrict__ xnb) {
    int row = blockIdx.x;
    int t = threadIdx.x;
    const float4* xr = (const float4*)(x + (size_t)row * NH);
    float4 xv = xr[t];
    float s  = xv.x + xv.y + xv.z + xv.w;
    float ss = xv.x*xv.x + xv.y*xv.y + xv.z*xv.z + xv.w*xv.w;
    for (int off = 32; off > 0; off >>= 1) {
        s  += __shfl_down(s, off);
        ss += __shfl_down(ss, off);
    }
    __shared__ float ls[4], lss[4];
    int wid = t >> 6;
    if ((t & 63) == 0) { ls[wid] = s; lss[wid] = ss; }
    __syncthreads();
    s  = ls[0] + ls[1] + ls[2] + ls[3];
    ss = lss[0] + lss[1] + lss[2] + lss[3];
    float mu  = s * (1.0f / NH);
    float var = ss * (1.0f / NH) - mu * mu;
    float rstd = rsqrtf(var + 1e-5f);
    float4 gv = ((const float4*)g)[t];
    float4 bv = ((const float4*)b)[t];
    float o0 = (xv.x - mu) * rstd * gv.x + bv.x;
    float o1 = (xv.y - mu) * rstd * gv.y + bv.y;
    float o2 = (xv.z - mu) * rstd * gv.z + bv.z;
    float o3 = (xv.w - mu) * rstd * gv.w + bv.w;
    uint2 u;
    u.x = pk_bf2(o0, o1);
    u.y = pk_bf2(o2, o3);
    *(uint2*)(xnb + (size_t)row * NH + t * 4) = u;
}

// ---------------- Kernel 1b: mask factor precompute ----------------
__global__ __launch_bounds__(256) void k_mask(const float* __restrict__ mask,
                                              float* __restrict__ maskf) {
    int i = blockIdx.x * 256 + threadIdx.x;
    maskf[i] = (1.0f - mask[i]) * 0.044194173824159216f * 0.69314718055994531f;
}

// ---------------- Kernel 2: Wv transpose + bf16: WvT[n][k] ----------------
__global__ __launch_bounds__(256) void k_wvt(const float* __restrict__ Wv,
                                             unsigned short* __restrict__ WvT) {
    __shared__ float T[64][65];
    int k0 = (blockIdx.x >> 4) * 64, n0 = (blockIdx.x & 15) * 64;
    int t = threadIdx.x;
    int row = t >> 2, c4 = t & 3;
#pragma unroll
    for (int s = 0; s < 4; ++s) {
        float4 v = *(const float4*)(Wv + (size_t)(k0 + row) * NH + n0 + c4 * 16 + s * 4);
        *(float4*)&T[row][c4 * 16 + s * 4] = v;
    }
    __syncthreads();
    unsigned short tmp[16] __attribute__((aligned(16)));
#pragma unroll
    for (int s = 0; s < 16; ++s) tmp[s] = f2bf(T[c4 * 16 + s][row]);
    unsigned short* dst = WvT + (size_t)(n0 + row) * NH + k0 + c4 * 16;
    *(short8*)dst = *(const short8*)&tmp[0];
    *(short8*)(dst + 8) = *(const short8*)&tmp[8];
}

// ---------------- Kernel 2b: [Wq|Wk] transpose to WqkT[64][1024] bf16 (rows 32..63 zero) ----------------
__global__ __launch_bounds__(256) void k_wqkt(const float* __restrict__ Wq,
                                              const float* __restrict__ Wk,
                                              unsigned short* __restrict__ WqkT) {
    int i = blockIdx.x * 256 + threadIdx.x;   // 65536 threads
    int n = i >> 10, k = i & 1023;
    float v = (n < 16) ? Wq[k * 16 + n] : (n < 32 ? Wk[k * 16 + (n - 16)] : 0.0f);
    WqkT[i] = f2bf(v);
}

// ---------------- Kernel 3: MFMA GEMM xn @ [Wv | Wq|Wk] -> vt bf16 + qT/kT f32 ----------------
__global__ __launch_bounds__(256) void k_vmfma(const unsigned short* __restrict__ Abf,
                                               const unsigned short* __restrict__ WvT,
                                               const unsigned short* __restrict__ WqkT,
                                               const float* __restrict__ bias,
                                               const float* __restrict__ bq,
                                               const float* __restrict__ bk,
                                               unsigned short* __restrict__ vt,
                                               float* __restrict__ qT,
                                               float* __restrict__ kT) {
    __shared__ unsigned short lds[2][8192];
    int t = threadIdx.x, w = t >> 6, lane = t & 63, g = lane >> 4, r = lane & 15;
    int nt_ = blockIdx.x % 17, mt = blockIdx.x / 17;
    int i0 = mt * 64, n0 = nt_ * 64;
    const unsigned short* Bsrc = (nt_ < 16) ? (WvT + (size_t)n0 * NH) : WqkT;

    f32x4 acc[2][2];
#pragma unroll
    for (int a = 0; a < 2; ++a)
#pragma unroll
        for (int c = 0; c < 2; ++c) acc[a][c] = (f32x4)(0.0f);

    auto stage = [&](int buf, int k0) {
#pragma unroll
        for (int i = 0; i < 2; ++i) {
            int o = i * 4096 + w * 1024 + lane * 16;
            int rr = o >> 7, cb = o & 127;
            int sc = (cb ^ ((rr & 7) << 4)) >> 1;
            gload16(Abf + (size_t)(i0 + rr) * NH + k0 + sc, &lds[buf][o >> 1]);
        }
#pragma unroll
        for (int i = 0; i < 2; ++i) {
            int o = i * 4096 + w * 1024 + lane * 16;
            int rr = o >> 7, cb = o & 127;
            int sc = (cb ^ ((rr & 7) << 4)) >> 1;
            gload16(Bsrc + (size_t)rr * NH + k0 + sc, &lds[buf][4096 + (o >> 1)]);
        }
    };

    int mbase = (w >> 1) * 32, nbase = (w & 1) * 32;
    int swz = (r & 7) << 4;

    auto compute = [&](int buf) {
        const unsigned short* As = lds[buf];
        const unsigned short* Bs = lds[buf] + 4096;
#pragma unroll
        for (int ks = 0; ks < 2; ++ks) {
            int kbyte = ks * 64 + g * 16;
            int kb = kbyte ^ swz;
            short8 af[2], bfm[2];
#pragma unroll
            for (int mf = 0; mf < 2; ++mf) {
                int row = mbase + mf * 16 + r;
                af[mf] = *(const short8*)(As + ((row * 128 + kb) >> 1));
            }
#pragma unroll
            for (int nf = 0; nf < 2; ++nf) {
                int rowB = nbase + nf * 16 + r;
                bfm[nf] = *(const short8*)(Bs + ((rowB * 128 + kb) >> 1));
            }
#pragma unroll
            for (int mf = 0; mf < 2; ++mf)
#pragma unroll
                for (int nf = 0; nf < 2; ++nf)
                    acc[mf][nf] = __builtin_amdgcn_mfma_f32_16x16x32_bf16(af[mf], bfm[nf], acc[mf][nf], 0, 0, 0);
        }
    };

    stage(0, 0);
    __syncthreads();
    int cur = 0;
#pragma unroll 1
    for (int kt = 0; kt < 15; ++kt) {
        stage(cur ^ 1, (kt + 1) * 64);
        compute(cur);
        __syncthreads();
        cur ^= 1;
    }
    compute(cur);

    if (nt_ < 16) {
        // v path: bias + bf16 + transpose into vt[b][h][d][j]
        unsigned short (*tsm)[72] = (unsigned short(*)[72])&lds[0][0];
#pragma unroll
        for (int nf = 0; nf < 2; ++nf) {
            float bv = bias[n0 + nbase + nf * 16 + r];
#pragma unroll
            for (int mf = 0; mf < 2; ++mf)
#pragma unroll
                for (int j = 0; j < 4; ++j)
                    tsm[nbase + nf * 16 + r][mbase + mf * 16 + g * 4 + j] = f2bf(acc[mf][nf][j] + bv);
        }
        __syncthreads();
        int b = mt >> 4;
        int jc0 = (mt & 15) * 64;
        int d = t >> 2, jb = (t & 3) * 16;
        unsigned short* dst = vt + ((size_t)((b * 16 + nt_) * 64 + d)) * 1024 + jc0 + jb;
        *(short8*)dst = *(const short8*)&tsm[d][jb];
        *(short8*)(dst + 8) = *(const short8*)&tsm[d][jb + 8];
    } else {
        // qk path: n<16 -> qT, 16<=n<32 -> kT (rows of WqkT 32..63 are zero, skipped)
#pragma unroll
        for (int nf = 0; nf < 2; ++nf) {
            int n = nbase + nf * 16 + r;
            if (n < 32) {
                float bb = (n < 16) ? bq[n] : bk[n - 16];
                float* dstp = (n < 16) ? (qT + n * 2048) : (kT + (n - 16) * 2048);
#pragma unroll
                for (int mf = 0; mf < 2; ++mf)
#pragma unroll
                    for (int j = 0; j < 4; ++j)
                        dstp[i0 + mbase + mf * 16 + g * 4 + j] = acc[mf][nf][j] + bb;
            }
        }
    }
}

// ---------------- Kernel 4: fused scores + MFMA PV, 32q/block, 4-way j-split, full prefetch ----------------
__global__ __launch_bounds__(256, 4) void k_attn(const float* __restrict__ qT,
                                                 const float* __restrict__ kT,
                                                 const unsigned short* __restrict__ vt,
                                                 const float* __restrict__ x,
                                                 const float* __restrict__ maskf,
                                                 const float* __restrict__ angle,
                                                 const float* __restrict__ zfp,
                                                 float* __restrict__ out) {
    // XCD-aware swizzle: 1024 = 8 * 128
    int bid = blockIdx.x;
    int lb = (bid & 7) * 128 + (bid >> 3);
    int qt = lb & 31;          // 32 q-tiles of 32 rows
    int h = (lb >> 5) & 15;
    int b = lb >> 9;
    int t = threadIdx.x;
    int w = t >> 6, lane = t & 63, g = lane >> 4, r = lane & 15;
    int i0 = qt * 32;

    __shared__ float red[4][3][32][20];

    float ang = angle[h];
    float cs = cosf(ang), sn = sinf(ang);
    float c1 = cs - sn, nc2 = -(cs + sn);
    float zf = zfp[0];
    const float L2E = 1.4426950408889634f;

    const float* qcol = qT + h * 2048 + b * 1024;
    const float* kcol = kT + h * 2048 + b * 1024;
    const float* mrow = maskf + b * 1024;
    const unsigned short* vhead = vt + ((size_t)(b * 16 + h)) * 64 * 1024;

    float qv0 = qcol[i0 + r];
    float qv1 = qcol[i0 + 16 + r];
    float c1q0 = c1 * qv0, snq0 = sn * qv0;
    float c1q1 = c1 * qv1, snq1 = sn * qv1;

    f32x4 acc[2][4];
#pragma unroll
    for (int m = 0; m < 2; ++m)
#pragma unroll
        for (int nb = 0; nb < 4; ++nb) acc[m][nb] = (f32x4)(0.0f);

    int jbase = w * 256 + g * 8;

    short8 bfr[2][4];
    float4 kv4[2][2], ff4[2][2];
#pragma unroll
    for (int nb = 0; nb < 4; ++nb)
        bfr[0][nb] = *(const short8*)(vhead + (size_t)(nb * 16 + r) * 1024 + jbase);
    kv4[0][0] = *(const float4*)(kcol + jbase);
    kv4[0][1] = *(const float4*)(kcol + jbase + 4);
    ff4[0][0] = *(const float4*)(mrow + jbase);
    ff4[0][1] = *(const float4*)(mrow + jbase + 4);

#pragma unroll 2
    for (int it = 0; it < 8; ++it) {
        int cur = it & 1, nxt = cur ^ 1;
        if (it < 7) {
            int jn = jbase + (it + 1) * 32;
#pragma unroll
            for (int nb = 0; nb < 4; ++nb)
                bfr[nxt][nb] = *(const short8*)(vhead + (size_t)(nb * 16 + r) * 1024 + jn);
            kv4[nxt][0] = *(const float4*)(kcol + jn);
            kv4[nxt][1] = *(const float4*)(kcol + jn + 4);
            ff4[nxt][0] = *(const float4*)(mrow + jn);
            ff4[nxt][1] = *(const float4*)(mrow + jn + 4);
        }
        float kk[8] = {kv4[cur][0].x, kv4[cur][0].y, kv4[cur][0].z, kv4[cur][0].w,
                       kv4[cur][1].x, kv4[cur][1].y, kv4[cur][1].z, kv4[cur][1].w};
        float ff[8] = {ff4[cur][0].x, ff4[cur][0].y, ff4[cur][0].z, ff4[cur][0].w,
                       ff4[cur][1].x, ff4[cur][1].y, ff4[cur][1].z, ff4[cur][1].w};

        unsigned a0[4], a1[4];
#pragma unroll
        for (int p = 0; p < 4; ++p) {
            float s0[2], s1[2];
#pragma unroll
            for (int q2 = 0; q2 < 2; ++q2) {
                float kv = kk[p * 2 + q2];
                float f  = ff[p * 2 + q2];
                float ck = nc2 * kv;
                float ik = cs * kv;
                float dd = c1q0 + ck;
                float im = snq0 + ik;
                float e  = __builtin_amdgcn_exp2f(-dd * L2E);
                float sg = __builtin_amdgcn_rcpf(1.0f + e);
                float comp = fmaf(dd, sg, im);
                float ee = __builtin_amdgcn_exp2f(comp * L2E);
                s0[q2] = __builtin_amdgcn_logf(1.0f + ee) * f;
                float dd1 = c1q1 + ck;
                float im1 = snq1 + ik;
                float e1  = __builtin_amdgcn_exp2f(-dd1 * L2E);
                float sg1 = __builtin_amdgcn_rcpf(1.0f + e1);
                float comp1 = fmaf(dd1, sg1, im1);
                float ee1 = __builtin_amdgcn_exp2f(comp1 * L2E);
                s1[q2] = __builtin_amdgcn_logf(1.0f + ee1) * f;
            }
            a0[p] = cvtpk_bf16(s0[0], s0[1]);
            a1[p] = cvtpk_bf16(s1[0], s1[1]);
        }
        unsigned av0[4] = {a0[0], a0[1], a0[2], a0[3]};
        unsigned av1[4] = {a1[0], a1[1], a1[2], a1[3]};
        short8 af0 = *(short8*)av0;
        short8 af1 = *(short8*)av1;

#pragma unroll
        for (int nb = 0; nb < 4; ++nb) {
            acc[0][nb] = __builtin_amdgcn_mfma_f32_16x16x32_bf16(af0, bfr[cur][nb], acc[0][nb], 0, 0, 0);
            acc[1][nb] = __builtin_amdgcn_mfma_f32_16x16x32_bf16(af1, bfr[cur][nb], acc[1][nb], 0, 0, 0);
        }
    }

    // cross-wave reduce: wave w owns nb==w
#pragma unroll
    for (int nb = 0; nb < 4; ++nb) {
        if (nb != w) {
            int idx = w - (w > nb ? 1 : 0);
#pragma unroll
            for (int m = 0; m < 2; ++m)
#pragma unroll
                for (int jj = 0; jj < 4; ++jj)
                    red[nb][idx][m * 16 + g * 4 + jj][r] = acc[m][nb][jj];
        }
    }
    __syncthreads();

#pragma unroll
    for (int m = 0; m < 2; ++m)
#pragma unroll
        for (int jj = 0; jj < 4; ++jj) {
            int lrow = m * 16 + g * 4 + jj;
            float c = acc[m][w][jj] + red[w][0][lrow][r]
                                    + red[w][1][lrow][r]
                                    + red[w][2][lrow][r];
            float gl = 0.5f * c * (1.0f + erff(c * 0.70710678118654752f));
            size_t base = ((size_t)(b * 1024 + i0 + lrow)) * 1024 + h * 64 + w * 16 + r;
            out[base] = x[base] + gl * zf;
        }
}

extern "C" void kernel_launch(void* const* d_in, const int* in_sizes, int n_in,
                              void* d_out, int out_size, void* d_ws, size_t ws_size,
                              hipStream_t stream) {
    const float* x      = (const float*)d_in[0];
    const float* mask   = (const float*)d_in[1];
    const float* Wq     = (const float*)d_in[2];
    const float* bq     = (const float*)d_in[3];
    const float* Wk     = (const float*)d_in[4];
    const float* bk     = (const float*)d_in[5];
    const float* Wv     = (const float*)d_in[6];
    const float* bv     = (const float*)d_in[7];
    const float* ln_g   = (const float*)d_in[8];
    const float* ln_b   = (const float*)d_in[9];
    const float* zf     = (const float*)d_in[10];
    const float* angle  = (const float*)d_in[11];
    float* out = (float*)d_out;

    unsigned short* xnb  = (unsigned short*)d_ws;   // 2M shorts
    unsigned short* vt   = xnb + 2097152;           // 2M shorts
    unsigned short* WvT  = vt + 2097152;            // 1M shorts
    unsigned short* WqkT = WvT + 1048576;           // 64K shorts
    float* qT    = (float*)(WqkT + 65536);          // 32K f32
    float* kT    = qT + 32768;                      // 32K f32
    float* maskf = kT + 32768;                      // 2K f32

    k_wvt<<<256, 256, 0, stream>>>(Wv, WvT);
    k_wqkt<<<256, 256, 0, stream>>>(Wq, Wk, WqkT);
    k_ln<<<BATCH * SEQ, 256, 0, stream>>>(x, ln_g, ln_b, xnb);
    k_mask<<<8, 256, 0, stream>>>(mask, maskf);
    k_vmfma<<<32 * 17, 256, 0, stream>>>(xnb, WvT, WqkT, bv, bq, bk, vt, qT, kT);
    k_attn<<<BATCH * NHEAD * (SEQ / 32), 256, 0, stream>>>(qT, kT, vt, x, maskf, angle, zf, out);
}